// Round 5
// baseline (426.878 us; speedup 1.0000x reference)
//
#include <hip/hip_runtime.h>
#include <hip/hip_bf16.h>
#include <cstdint>

#define BB   4
#define TT   2048
#define HH   1024
#define NHH  16
#define DHH  64
#define MM   (BB*TT)      // 8192
#define N3   (3*HH)       // 3072

typedef __attribute__((ext_vector_type(8))) short short8;   // 8 bf16 = 4 VGPR
typedef __attribute__((ext_vector_type(4))) float f32x4;

#if __has_builtin(__builtin_amdgcn_exp2f)
#define EXP2F(x) __builtin_amdgcn_exp2f(x)
#else
#define EXP2F(x) exp2f(x)
#endif

// Q pre-scale: (1/sqrt(DH)) * log2(e)  so scores are in log2 domain
#define QSCALE 0.1803368801111204f

__device__ __forceinline__ float bf2f(unsigned short u) {
    return __uint_as_float(((uint32_t)u) << 16);
}
__device__ __forceinline__ unsigned short f2bf(float f) {
    uint32_t u = __float_as_uint(f);
    return (unsigned short)((u + 0x7fffu + ((u >> 16) & 1u)) >> 16);  // RNE
}
__device__ __forceinline__ void gload_lds16(const unsigned short* g, unsigned short* l) {
    __builtin_amdgcn_global_load_lds(
        (const __attribute__((address_space(1))) uint32_t*)g,
        (__attribute__((address_space(3))) uint32_t*)l, 16, 0, 0);
}

// ---------------------------------------------------------------------------
// f32 -> bf16 bulk convert (x)
// ---------------------------------------------------------------------------
__global__ __launch_bounds__(256) void cvt_bf16(
    const float* __restrict__ src, unsigned short* __restrict__ dst, int n4)
{
    int i = blockIdx.x * 256 + threadIdx.x;
    const int stride = gridDim.x * 256;
    for (; i < n4; i += stride) {
        float4 v = ((const float4*)src)[i];
        ushort4 o;
        o.x = f2bf(v.x); o.y = f2bf(v.y); o.z = f2bf(v.z); o.w = f2bf(v.w);
        ((ushort4*)dst)[i] = o;
    }
}

// all three weight matrices in one launch (blockIdx.y selects)
__global__ __launch_bounds__(256) void cvt_w3(
    const float* __restrict__ Wq, const float* __restrict__ Wk,
    const float* __restrict__ Wv, unsigned short* __restrict__ Wb)
{
    const float* src = (blockIdx.y == 0) ? Wq : (blockIdx.y == 1 ? Wk : Wv);
    unsigned short* dst = Wb + (size_t)blockIdx.y * HH * HH;
    const int n4 = HH * HH / 4;
    int i = blockIdx.x * 256 + threadIdx.x;
    const int stride = gridDim.x * 256;
    for (; i < n4; i += stride) {
        float4 v = ((const float4*)src)[i];
        ushort4 o;
        o.x = f2bf(v.x); o.y = f2bf(v.y); o.z = f2bf(v.z); o.w = f2bf(v.w);
        ((ushort4*)dst)[i] = o;
    }
}

// ---------------------------------------------------------------------------
// QKV projection (MFMA 16x16x32, 128x128 tile, BK=32, global_load_lds).
// Epilogue writes packed per-head tensors qp/kp/vp[b][h][t][64] (bf16);
// Q slab pre-scaled by QSCALE so attention uses native exp2.
// ---------------------------------------------------------------------------
__global__ __launch_bounds__(256) void proj_mfma(
    const unsigned short* __restrict__ xb, const unsigned short* __restrict__ Wb,
    unsigned short* __restrict__ qp, unsigned short* __restrict__ kp,
    unsigned short* __restrict__ vp)
{
    __shared__ unsigned short As[4096];   // 4 kc * 128 m * 8
    __shared__ unsigned short Bs[4096];
    const int m0 = blockIdx.x * 128;
    const int n0 = blockIdx.y * 128;
    const int sel = n0 >> 10;
    const unsigned short* Wbase = Wb + (size_t)sel * HH * HH;
    const int nw0 = n0 & (HH - 1);
    const int tid = threadIdx.x;
    const int wave = tid >> 6, lane = tid & 63;
    const int quad = lane >> 4, l15 = lane & 15;
    const int wm = wave >> 1, wn = wave & 1;

    f32x4 acc[4][4];
    #pragma unroll
    for (int i = 0; i < 4; ++i)
        #pragma unroll
        for (int j = 0; j < 4; ++j) acc[i][j] = (f32x4){0.f, 0.f, 0.f, 0.f};

    for (int k0 = 0; k0 < HH; k0 += 32) {
        __syncthreads();
        #pragma unroll
        for (int q = 0; q < 2; ++q) {
            const int chunk = (wave * 2 + q) * 64 + lane;   // 0..511
            const int kc = chunk >> 7, mrow = chunk & 127;
            gload_lds16(xb    + (size_t)(m0  + mrow) * HH + k0 + kc * 8, As + chunk * 8);
            gload_lds16(Wbase + (size_t)(nw0 + mrow) * HH + k0 + kc * 8, Bs + chunk * 8);
        }
        __syncthreads();
        short8 af[4], bf[4];
        #pragma unroll
        for (int i = 0; i < 4; ++i)
            af[i] = *(const short8*)&As[(quad * 128 + wm * 64 + i * 16 + l15) * 8];
        #pragma unroll
        for (int j = 0; j < 4; ++j)
            bf[j] = *(const short8*)&Bs[(quad * 128 + wn * 64 + j * 16 + l15) * 8];
        #pragma unroll
        for (int i = 0; i < 4; ++i)
            #pragma unroll
            for (int j = 0; j < 4; ++j)
                acc[i][j] = __builtin_amdgcn_mfma_f32_16x16x32_bf16(af[i], bf[j], acc[i][j], 0, 0, 0);
    }
    unsigned short* outp = (sel == 0) ? qp : (sel == 1 ? kp : vp);
    const float cscale = (sel == 0) ? QSCALE : 1.0f;
    #pragma unroll
    for (int i = 0; i < 4; ++i)
        #pragma unroll
        for (int j = 0; j < 4; ++j) {
            const int col = n0 + wn * 64 + j * 16 + l15;
            const int hh2 = (col >> 6) & (NHH - 1);
            const int dd  = col & (DHH - 1);
            #pragma unroll
            for (int r = 0; r < 4; ++r) {
                const int row = m0 + wm * 64 + i * 16 + quad * 4 + r;
                const int bb2 = row >> 11, tt2 = row & (TT - 1);
                outp[((size_t)(bb2 * NHH + hh2) * TT + tt2) * DHH + dd] =
                    f2bf(acc[i][j][r] * cscale);
            }
        }
}

// ---------------------------------------------------------------------------
// Fused attention, 512 threads (8 waves), t-block 128, per-wave 256-s stripe:
//   phase 1: l_t = sum_s exp2(S[t,s]);  linv[t] = 1/(l_t*T)
//   phase 2: a[b,h,s] += sum_t exp2(S[t,s]) * linv[t]   (atomics)
// K fragments prefetched 2 ssteps ahead; no LDS in the hot loop.
// ---------------------------------------------------------------------------
__global__ __launch_bounds__(512) void attn_fused(
    const unsigned short* __restrict__ qp, const unsigned short* __restrict__ kp,
    float* __restrict__ a)
{
    const int t0 = blockIdx.x * 128;   // 16 t-blocks
    const int h = blockIdx.y, b = blockIdx.z;
    const int bh = b * NHH + h;
    const int tid = threadIdx.x;
    const int wave = tid >> 6, lane = tid & 63;
    const int quad = lane >> 4, l15 = lane & 15;
    __shared__ float red[8][128];
    __shared__ float linv[128];

    const unsigned short* q = qp + (size_t)bh * TT * DHH;
    const unsigned short* kptr =
        kp + (size_t)bh * TT * DHH + (size_t)(wave * 256 + l15) * DHH + quad * 8;

    // A-frags: 8 row-groups of 16 t; k split 0..31 / 32..63 (shared by waves)
    short8 aq[8][2];
    #pragma unroll
    for (int i = 0; i < 8; ++i)
        #pragma unroll
        for (int c = 0; c < 2; ++c)
            aq[i][c] = *(const short8*)&q[(size_t)(t0 + i * 16 + l15) * DHH + quad * 8 + c * 32];

#define KLD(ss, c) (*(const short8*)(kptr + (size_t)(ss) * 16 * DHH + (c) * 32))

    // ---- phase 1: row sums ----
    float rs[8][4];
    #pragma unroll
    for (int i = 0; i < 8; ++i)
        #pragma unroll
        for (int r = 0; r < 4; ++r) rs[i][r] = 0.f;

    {
        short8 c0a = KLD(0, 0), c0b = KLD(0, 1);
        short8 c1a = KLD(1, 0), c1b = KLD(1, 1);
        for (int ss = 0; ss < 16; ++ss) {
            const short8 ba = c0a, bb = c0b;
            c0a = c1a; c0b = c1b;
            if (ss < 14) { c1a = KLD(ss + 2, 0); c1b = KLD(ss + 2, 1); }
            #pragma unroll
            for (int i = 0; i < 8; ++i) {
                f32x4 c = (f32x4){0.f, 0.f, 0.f, 0.f};
                c = __builtin_amdgcn_mfma_f32_16x16x32_bf16(aq[i][0], ba, c, 0, 0, 0);
                c = __builtin_amdgcn_mfma_f32_16x16x32_bf16(aq[i][1], bb, c, 0, 0, 0);
                #pragma unroll
                for (int r = 0; r < 4; ++r) rs[i][r] += EXP2F(c[r]);
            }
        }
    }
    #pragma unroll
    for (int off = 1; off < 16; off <<= 1)
        #pragma unroll
        for (int i = 0; i < 8; ++i)
            #pragma unroll
            for (int r = 0; r < 4; ++r) rs[i][r] += __shfl_xor(rs[i][r], off);
    if (l15 == 0)
        #pragma unroll
        for (int i = 0; i < 8; ++i)
            #pragma unroll
            for (int r = 0; r < 4; ++r) red[wave][i * 16 + quad * 4 + r] = rs[i][r];
    __syncthreads();
    if (tid < 128) {
        float l = 0.f;
        #pragma unroll
        for (int w = 0; w < 8; ++w) l += red[w][tid];
        linv[tid] = 1.0f / (l * (float)TT);
    }
    __syncthreads();

    // ---- phase 2: column sums ----
    float lrv[8][4];
    #pragma unroll
    for (int i = 0; i < 8; ++i)
        #pragma unroll
        for (int r = 0; r < 4; ++r) lrv[i][r] = linv[i * 16 + quad * 4 + r];

    {
        short8 c0a = KLD(0, 0), c0b = KLD(0, 1);
        short8 c1a = KLD(1, 0), c1b = KLD(1, 1);
        for (int ss = 0; ss < 16; ++ss) {
            const short8 ba = c0a, bb = c0b;
            c0a = c1a; c0b = c1b;
            if (ss < 14) { c1a = KLD(ss + 2, 0); c1b = KLD(ss + 2, 1); }
            float cs = 0.f;
            #pragma unroll
            for (int i = 0; i < 8; ++i) {
                f32x4 c = (f32x4){0.f, 0.f, 0.f, 0.f};
                c = __builtin_amdgcn_mfma_f32_16x16x32_bf16(aq[i][0], ba, c, 0, 0, 0);
                c = __builtin_amdgcn_mfma_f32_16x16x32_bf16(aq[i][1], bb, c, 0, 0, 0);
                #pragma unroll
                for (int r = 0; r < 4; ++r) cs += EXP2F(c[r]) * lrv[i][r];
            }
            cs += __shfl_xor(cs, 16);
            cs += __shfl_xor(cs, 32);
            if (lane < 16)
                atomicAdd(&a[(size_t)bh * TT + wave * 256 + ss * 16 + l15], cs);
        }
    }
#undef KLD
}

// ---------------------------------------------------------------------------
// cm[b, h*64+d] += sum_{s in slab} a[b,h,s] * V[b,h,s,d]  — vectorized:
// thread = (s-group 0..31, d-octet 0..7), short8 V loads.
// ---------------------------------------------------------------------------
__global__ __launch_bounds__(256) void ctx_mean(
    const unsigned short* __restrict__ vp, const float* __restrict__ a,
    float* __restrict__ cm)
{
    const int h = blockIdx.x, b = blockIdx.y, sb = blockIdx.z;
    const int tid = threadIdx.x;
    const int oct = tid & 7, sgrp = tid >> 3;   // 32 s-groups x 8 octets
    const int bh = b * NHH + h;
    __shared__ float red[32][72];               // [sgrp][d], padded
    float pa[8];
    #pragma unroll
    for (int j = 0; j < 8; ++j) pa[j] = 0.f;
    for (int s = sb * 256 + sgrp; s < sb * 256 + 256; s += 32) {
        const float av = a[(size_t)bh * TT + s];
        short8 v = *(const short8*)&vp[((size_t)bh * TT + s) * DHH + oct * 8];
        #pragma unroll
        for (int j = 0; j < 8; ++j)
            pa[j] += av * bf2f((unsigned short)v[j]);
    }
    #pragma unroll
    for (int j = 0; j < 8; ++j) red[sgrp][oct * 8 + j] = pa[j];
    __syncthreads();
    if (tid < 64) {
        float s = 0.f;
        #pragma unroll
        for (int g = 0; g < 32; ++g) s += red[g][tid];
        atomicAdd(&cm[b * HH + h * DHH + tid], s);
    }
}

// ---------------------------------------------------------------------------
// out[b][j] = bo[j] + sum_k cm[b][k] * Wo[j][k]
// ---------------------------------------------------------------------------
__global__ __launch_bounds__(256) void out_proj(
    const float* __restrict__ cm, const float* __restrict__ Wo,
    const float* __restrict__ bo, float* __restrict__ out)
{
    const int b = blockIdx.y;
    const int jb = blockIdx.x;
    const int tid = threadIdx.x;
    const int j = jb * 64 + (tid >> 2);
    const int kg = tid & 3;
    __shared__ float cs[HH];
    for (int k = tid; k < HH; k += 256) cs[k] = cm[b * HH + k];
    __syncthreads();
    float acc = 0.f;
    const float* wrow = &Wo[(size_t)j * HH];
    #pragma unroll 8
    for (int i = 0; i < 64; ++i) {
        const int k = kg * 256 + i * 4;
        float4 w4 = *(const float4*)&wrow[k];
        acc += w4.x * cs[k] + w4.y * cs[k+1] + w4.z * cs[k+2] + w4.w * cs[k+3];
    }
    acc += __shfl_down(acc, 2, 4);
    acc += __shfl_down(acc, 1, 4);
    if (kg == 0) out[b * HH + j] = acc + bo[j];
}

// ---------------------------------------------------------------------------
extern "C" void kernel_launch(void* const* d_in, const int* in_sizes, int n_in,
                              void* d_out, int out_size, void* d_ws, size_t ws_size,
                              hipStream_t stream) {
    const float* x  = (const float*)d_in[0];
    const float* Wq = (const float*)d_in[1];
    const float* Wk = (const float*)d_in[2];
    const float* Wv = (const float*)d_in[3];
    const float* Wo = (const float*)d_in[4];
    const float* bo = (const float*)d_in[5];
    float* out = (float*)d_out;

    char* ws = (char*)d_ws;
    unsigned short* qp = (unsigned short*)ws;  ws += (size_t)MM * HH * 2;  // 16.78 MB
    unsigned short* kp = (unsigned short*)ws;  ws += (size_t)MM * HH * 2;
    unsigned short* vp = (unsigned short*)ws;  ws += (size_t)MM * HH * 2;
    unsigned short* xb = (unsigned short*)ws;  ws += (size_t)MM * HH * 2;
    unsigned short* Wb = (unsigned short*)ws;  ws += (size_t)3 * HH * HH * 2;
    float* a  = (float*)ws;                    ws += (size_t)BB * NHH * TT * 4;
    float* cm = (float*)ws;

    hipMemsetAsync(a, 0, (size_t)(BB * NHH * TT + BB * HH) * 4, stream);  // a + cm

    cvt_bf16<<<2048, 256, 0, stream>>>(x, xb, MM * HH / 4);
    cvt_w3  <<<dim3(512, 3), 256, 0, stream>>>(Wq, Wk, Wv, Wb);

    proj_mfma <<<dim3(64, 24),      256, 0, stream>>>(xb, Wb, qp, kp, vp);
    attn_fused<<<dim3(16, NHH, BB), 512, 0, stream>>>(qp, kp, a);
    ctx_mean  <<<dim3(NHH, BB, 8),  256, 0, stream>>>(vp, a, cm);
    out_proj  <<<dim3(16, BB),      256, 0, stream>>>(cm, Wo, bo, out);
}

// Round 6
// 367.516 us; speedup vs baseline: 1.1615x; 1.1615x over previous
//
#include <hip/hip_runtime.h>
#include <hip/hip_bf16.h>
#include <cstdint>

#define BB   4
#define TT   2048
#define HH   1024
#define NHH  16
#define DHH  64
#define MM   (BB*TT)      // 8192
#define N3   (3*HH)       // 3072

typedef __attribute__((ext_vector_type(8))) short short8;   // 8 bf16 = 4 VGPR
typedef __attribute__((ext_vector_type(4))) float f32x4;

#if __has_builtin(__builtin_amdgcn_exp2f)
#define EXP2F(x) __builtin_amdgcn_exp2f(x)
#else
#define EXP2F(x) exp2f(x)
#endif

// Q pre-scale: (1/sqrt(DH)) * log2(e)  so scores are in log2 domain
#define QSCALE 0.1803368801111204f

__device__ __forceinline__ float bf2f(unsigned short u) {
    return __uint_as_float(((uint32_t)u) << 16);
}
__device__ __forceinline__ unsigned short f2bf(float f) {
    uint32_t u = __float_as_uint(f);
    return (unsigned short)((u + 0x7fffu + ((u >> 16) & 1u)) >> 16);  // RNE
}
__device__ __forceinline__ void gload_lds16(const unsigned short* g, unsigned short* l) {
    __builtin_amdgcn_global_load_lds(
        (const __attribute__((address_space(1))) uint32_t*)g,
        (__attribute__((address_space(3))) uint32_t*)l, 16, 0, 0);
}

// ---------------------------------------------------------------------------
// f32 -> bf16 bulk convert (x)
// ---------------------------------------------------------------------------
__global__ __launch_bounds__(256) void cvt_bf16(
    const float* __restrict__ src, unsigned short* __restrict__ dst, int n4)
{
    int i = blockIdx.x * 256 + threadIdx.x;
    const int stride = gridDim.x * 256;
    for (; i < n4; i += stride) {
        float4 v = ((const float4*)src)[i];
        ushort4 o;
        o.x = f2bf(v.x); o.y = f2bf(v.y); o.z = f2bf(v.z); o.w = f2bf(v.w);
        ((ushort4*)dst)[i] = o;
    }
}

// all three weight matrices in one launch (blockIdx.y selects)
__global__ __launch_bounds__(256) void cvt_w3(
    const float* __restrict__ Wq, const float* __restrict__ Wk,
    const float* __restrict__ Wv, unsigned short* __restrict__ Wb)
{
    const float* src = (blockIdx.y == 0) ? Wq : (blockIdx.y == 1 ? Wk : Wv);
    unsigned short* dst = Wb + (size_t)blockIdx.y * HH * HH;
    const int n4 = HH * HH / 4;
    int i = blockIdx.x * 256 + threadIdx.x;
    const int stride = gridDim.x * 256;
    for (; i < n4; i += stride) {
        float4 v = ((const float4*)src)[i];
        ushort4 o;
        o.x = f2bf(v.x); o.y = f2bf(v.y); o.z = f2bf(v.z); o.w = f2bf(v.w);
        ((ushort4*)dst)[i] = o;
    }
}

// ---------------------------------------------------------------------------
// QKV projection (MFMA 16x16x32, 128x128 tile, BK=32, global_load_lds).
// Epilogue writes packed per-head tensors qp/kp/vp[b][h][t][64] (bf16);
// Q slab pre-scaled by QSCALE so attention uses native exp2.
// ---------------------------------------------------------------------------
__global__ __launch_bounds__(256) void proj_mfma(
    const unsigned short* __restrict__ xb, const unsigned short* __restrict__ Wb,
    unsigned short* __restrict__ qp, unsigned short* __restrict__ kp,
    unsigned short* __restrict__ vp)
{
    __shared__ unsigned short As[4096];   // 4 kc * 128 m * 8
    __shared__ unsigned short Bs[4096];
    const int m0 = blockIdx.x * 128;
    const int n0 = blockIdx.y * 128;
    const int sel = n0 >> 10;
    const unsigned short* Wbase = Wb + (size_t)sel * HH * HH;
    const int nw0 = n0 & (HH - 1);
    const int tid = threadIdx.x;
    const int wave = tid >> 6, lane = tid & 63;
    const int quad = lane >> 4, l15 = lane & 15;
    const int wm = wave >> 1, wn = wave & 1;

    f32x4 acc[4][4];
    #pragma unroll
    for (int i = 0; i < 4; ++i)
        #pragma unroll
        for (int j = 0; j < 4; ++j) acc[i][j] = (f32x4){0.f, 0.f, 0.f, 0.f};

    for (int k0 = 0; k0 < HH; k0 += 32) {
        __syncthreads();
        #pragma unroll
        for (int q = 0; q < 2; ++q) {
            const int chunk = (wave * 2 + q) * 64 + lane;   // 0..511
            const int kc = chunk >> 7, mrow = chunk & 127;
            gload_lds16(xb    + (size_t)(m0  + mrow) * HH + k0 + kc * 8, As + chunk * 8);
            gload_lds16(Wbase + (size_t)(nw0 + mrow) * HH + k0 + kc * 8, Bs + chunk * 8);
        }
        __syncthreads();
        short8 af[4], bf[4];
        #pragma unroll
        for (int i = 0; i < 4; ++i)
            af[i] = *(const short8*)&As[(quad * 128 + wm * 64 + i * 16 + l15) * 8];
        #pragma unroll
        for (int j = 0; j < 4; ++j)
            bf[j] = *(const short8*)&Bs[(quad * 128 + wn * 64 + j * 16 + l15) * 8];
        #pragma unroll
        for (int i = 0; i < 4; ++i)
            #pragma unroll
            for (int j = 0; j < 4; ++j)
                acc[i][j] = __builtin_amdgcn_mfma_f32_16x16x32_bf16(af[i], bf[j], acc[i][j], 0, 0, 0);
    }
    unsigned short* outp = (sel == 0) ? qp : (sel == 1 ? kp : vp);
    const float cscale = (sel == 0) ? QSCALE : 1.0f;
    #pragma unroll
    for (int i = 0; i < 4; ++i)
        #pragma unroll
        for (int j = 0; j < 4; ++j) {
            const int col = n0 + wn * 64 + j * 16 + l15;
            const int hh2 = (col >> 6) & (NHH - 1);
            const int dd  = col & (DHH - 1);
            #pragma unroll
            for (int r = 0; r < 4; ++r) {
                const int row = m0 + wm * 64 + i * 16 + quad * 4 + r;
                const int bb2 = row >> 11, tt2 = row & (TT - 1);
                outp[((size_t)(bb2 * NHH + hh2) * TT + tt2) * DHH + dd] =
                    f2bf(acc[i][j][r] * cscale);
            }
        }
}

// ---------------------------------------------------------------------------
// Fused attention, 256 threads (4 waves), t-block 64, per-wave 512-s stripe:
//   phase 1: l_t = sum_s exp2(S[t,s]);  linv[t] = 1/(l_t*T)
//   phase 2: a[b,h,s] += sum_t exp2(S[t,s]) * linv[t]   (atomics)
// Small register footprint (aq[4][2]) for high occupancy; K prefetch depth 2.
// ---------------------------------------------------------------------------
__global__ __launch_bounds__(256) void attn_fused(
    const unsigned short* __restrict__ qp, const unsigned short* __restrict__ kp,
    float* __restrict__ a)
{
    const int t0 = blockIdx.x * 64;    // 32 t-blocks
    const int h = blockIdx.y, b = blockIdx.z;
    const int bh = b * NHH + h;
    const int tid = threadIdx.x;
    const int wave = tid >> 6, lane = tid & 63;
    const int quad = lane >> 4, l15 = lane & 15;
    __shared__ float red[4][64];
    __shared__ float linv[64];

    const unsigned short* q = qp + (size_t)bh * TT * DHH;
    const unsigned short* kptr =
        kp + (size_t)bh * TT * DHH + (size_t)(wave * 512 + l15) * DHH + quad * 8;

    // A-frags: 4 row-groups of 16 t; k split 0..31 / 32..63 (shared by waves)
    short8 aq[4][2];
    #pragma unroll
    for (int i = 0; i < 4; ++i)
        #pragma unroll
        for (int c = 0; c < 2; ++c)
            aq[i][c] = *(const short8*)&q[(size_t)(t0 + i * 16 + l15) * DHH + quad * 8 + c * 32];

#define KLD(ss, c) (*(const short8*)(kptr + (size_t)(ss) * 16 * DHH + (c) * 32))

    // ---- phase 1: row sums ----
    float rs[4][4];
    #pragma unroll
    for (int i = 0; i < 4; ++i)
        #pragma unroll
        for (int r = 0; r < 4; ++r) rs[i][r] = 0.f;

    {
        short8 c0a = KLD(0, 0), c0b = KLD(0, 1);
        short8 c1a = KLD(1, 0), c1b = KLD(1, 1);
        for (int ss = 0; ss < 32; ++ss) {
            const short8 ba = c0a, bb = c0b;
            c0a = c1a; c0b = c1b;
            if (ss < 30) { c1a = KLD(ss + 2, 0); c1b = KLD(ss + 2, 1); }
            #pragma unroll
            for (int i = 0; i < 4; ++i) {
                f32x4 c = (f32x4){0.f, 0.f, 0.f, 0.f};
                c = __builtin_amdgcn_mfma_f32_16x16x32_bf16(aq[i][0], ba, c, 0, 0, 0);
                c = __builtin_amdgcn_mfma_f32_16x16x32_bf16(aq[i][1], bb, c, 0, 0, 0);
                #pragma unroll
                for (int r = 0; r < 4; ++r) rs[i][r] += EXP2F(c[r]);
            }
        }
    }
    #pragma unroll
    for (int off = 1; off < 16; off <<= 1)
        #pragma unroll
        for (int i = 0; i < 4; ++i)
            #pragma unroll
            for (int r = 0; r < 4; ++r) rs[i][r] += __shfl_xor(rs[i][r], off);
    if (l15 == 0)
        #pragma unroll
        for (int i = 0; i < 4; ++i)
            #pragma unroll
            for (int r = 0; r < 4; ++r) red[wave][i * 16 + quad * 4 + r] = rs[i][r];
    __syncthreads();
    if (tid < 64) {
        const float l = red[0][tid] + red[1][tid] + red[2][tid] + red[3][tid];
        linv[tid] = 1.0f / (l * (float)TT);
    }
    __syncthreads();

    // ---- phase 2: column sums ----
    float lrv[4][4];
    #pragma unroll
    for (int i = 0; i < 4; ++i)
        #pragma unroll
        for (int r = 0; r < 4; ++r) lrv[i][r] = linv[i * 16 + quad * 4 + r];

    {
        short8 c0a = KLD(0, 0), c0b = KLD(0, 1);
        short8 c1a = KLD(1, 0), c1b = KLD(1, 1);
        for (int ss = 0; ss < 32; ++ss) {
            const short8 ba = c0a, bb = c0b;
            c0a = c1a; c0b = c1b;
            if (ss < 30) { c1a = KLD(ss + 2, 0); c1b = KLD(ss + 2, 1); }
            float cs = 0.f;
            #pragma unroll
            for (int i = 0; i < 4; ++i) {
                f32x4 c = (f32x4){0.f, 0.f, 0.f, 0.f};
                c = __builtin_amdgcn_mfma_f32_16x16x32_bf16(aq[i][0], ba, c, 0, 0, 0);
                c = __builtin_amdgcn_mfma_f32_16x16x32_bf16(aq[i][1], bb, c, 0, 0, 0);
                #pragma unroll
                for (int r = 0; r < 4; ++r) cs += EXP2F(c[r]) * lrv[i][r];
            }
            cs += __shfl_xor(cs, 16);
            cs += __shfl_xor(cs, 32);
            if (lane < 16)
                atomicAdd(&a[(size_t)bh * TT + wave * 512 + ss * 16 + l15], cs);
        }
    }
#undef KLD
}

// ---------------------------------------------------------------------------
// cm[b, h*64+d] += sum_{s in slab} a[b,h,s] * V[b,h,s,d]  — vectorized:
// thread = (s-group 0..31, d-octet 0..7), short8 V loads.
// ---------------------------------------------------------------------------
__global__ __launch_bounds__(256) void ctx_mean(
    const unsigned short* __restrict__ vp, const float* __restrict__ a,
    float* __restrict__ cm)
{
    const int h = blockIdx.x, b = blockIdx.y, sb = blockIdx.z;
    const int tid = threadIdx.x;
    const int oct = tid & 7, sgrp = tid >> 3;   // 32 s-groups x 8 octets
    const int bh = b * NHH + h;
    __shared__ float red[32][72];               // [sgrp][d], padded
    float pa[8];
    #pragma unroll
    for (int j = 0; j < 8; ++j) pa[j] = 0.f;
    for (int s = sb * 256 + sgrp; s < sb * 256 + 256; s += 32) {
        const float av = a[(size_t)bh * TT + s];
        short8 v = *(const short8*)&vp[((size_t)bh * TT + s) * DHH + oct * 8];
        #pragma unroll
        for (int j = 0; j < 8; ++j)
            pa[j] += av * bf2f((unsigned short)v[j]);
    }
    #pragma unroll
    for (int j = 0; j < 8; ++j) red[sgrp][oct * 8 + j] = pa[j];
    __syncthreads();
    if (tid < 64) {
        float s = 0.f;
        #pragma unroll
        for (int g = 0; g < 32; ++g) s += red[g][tid];
        atomicAdd(&cm[b * HH + h * DHH + tid], s);
    }
}

// ---------------------------------------------------------------------------
// out[b][j] = bo[j] + sum_k cm[b][k] * Wo[j][k]
// ---------------------------------------------------------------------------
__global__ __launch_bounds__(256) void out_proj(
    const float* __restrict__ cm, const float* __restrict__ Wo,
    const float* __restrict__ bo, float* __restrict__ out)
{
    const int b = blockIdx.y;
    const int jb = blockIdx.x;
    const int tid = threadIdx.x;
    const int j = jb * 64 + (tid >> 2);
    const int kg = tid & 3;
    __shared__ float cs[HH];
    for (int k = tid; k < HH; k += 256) cs[k] = cm[b * HH + k];
    __syncthreads();
    float acc = 0.f;
    const float* wrow = &Wo[(size_t)j * HH];
    #pragma unroll 8
    for (int i = 0; i < 64; ++i) {
        const int k = kg * 256 + i * 4;
        float4 w4 = *(const float4*)&wrow[k];
        acc += w4.x * cs[k] + w4.y * cs[k+1] + w4.z * cs[k+2] + w4.w * cs[k+3];
    }
    acc += __shfl_down(acc, 2, 4);
    acc += __shfl_down(acc, 1, 4);
    if (kg == 0) out[b * HH + j] = acc + bo[j];
}

// ---------------------------------------------------------------------------
extern "C" void kernel_launch(void* const* d_in, const int* in_sizes, int n_in,
                              void* d_out, int out_size, void* d_ws, size_t ws_size,
                              hipStream_t stream) {
    const float* x  = (const float*)d_in[0];
    const float* Wq = (const float*)d_in[1];
    const float* Wk = (const float*)d_in[2];
    const float* Wv = (const float*)d_in[3];
    const float* Wo = (const float*)d_in[4];
    const float* bo = (const float*)d_in[5];
    float* out = (float*)d_out;

    char* ws = (char*)d_ws;
    unsigned short* qp = (unsigned short*)ws;  ws += (size_t)MM * HH * 2;  // 16.78 MB
    unsigned short* kp = (unsigned short*)ws;  ws += (size_t)MM * HH * 2;
    unsigned short* vp = (unsigned short*)ws;  ws += (size_t)MM * HH * 2;
    unsigned short* xb = (unsigned short*)ws;  ws += (size_t)MM * HH * 2;
    unsigned short* Wb = (unsigned short*)ws;  ws += (size_t)3 * HH * HH * 2;
    float* a  = (float*)ws;                    ws += (size_t)BB * NHH * TT * 4;
    float* cm = (float*)ws;

    hipMemsetAsync(a, 0, (size_t)(BB * NHH * TT + BB * HH) * 4, stream);  // a + cm

    cvt_bf16<<<2048, 256, 0, stream>>>(x, xb, MM * HH / 4);
    cvt_w3  <<<dim3(512, 3), 256, 0, stream>>>(Wq, Wk, Wv, Wb);

    proj_mfma <<<dim3(64, 24),      256, 0, stream>>>(xb, Wb, qp, kp, vp);
    attn_fused<<<dim3(32, NHH, BB), 256, 0, stream>>>(qp, kp, a);
    ctx_mean  <<<dim3(NHH, BB, 8),  256, 0, stream>>>(vp, a, cm);
    out_proj  <<<dim3(16, BB),      256, 0, stream>>>(cm, Wo, bo, out);
}